// Round 6
// baseline (156.803 us; speedup 1.0000x reference)
//
#include <hip/hip_runtime.h>

#define D_MODEL 512
#define DFF 2048
#define NEXP 8
#define LTOK 4096          // B*N tokens
#define NPAIR 8192         // LTOK * K
#define PMAX 9216          // padded gathered rows (8192 + 8*128)
#define MAXT 72            // max 128-row M-tiles

// hdr (int) offsets within ws
#define HD_COUNTS 0
#define HD_CURSOR 8
#define HD_OFF    16
#define HD_NTILES 25
#define HD_TILE_E 32
#define HD_TILE_R 112

typedef __attribute__((ext_vector_type(8))) short bf16x8;
typedef __attribute__((ext_vector_type(4))) float f32x4;

__device__ __forceinline__ unsigned short f2bf(float f){
  unsigned u = __builtin_bit_cast(unsigned, f);
  u += 0x7fffu + ((u>>16)&1u);        // RNE round to bf16
  return (unsigned short)(u>>16);
}

template<int N> __device__ __forceinline__ void wait_vm(){
  if constexpr (N==6)      asm volatile("s_waitcnt vmcnt(6)" ::: "memory");
  else                     asm volatile("s_waitcnt vmcnt(0)" ::: "memory");
}
#define RAW_BARRIER() asm volatile("s_barrier" ::: "memory")

// ------- fused prep: blocks [0,8192) convert w1/w2 -> bf16; [8192,9216) router -------
__global__ void prep_kernel(const float* __restrict__ w1, const float* __restrict__ w2,
                            unsigned short* __restrict__ w1b, unsigned short* __restrict__ w2b,
                            const float* __restrict__ x, const float* __restrict__ rw,
                            int* __restrict__ pair_e, float* __restrict__ pair_w){
  int bx = blockIdx.x;
  int tid = threadIdx.x;
  if (bx < 8192){
    // ---- weight convert: one thread per 8 elements ----
    int id = bx*256 + tid;
    const int per = NEXP*DFF*D_MODEL/8;        // 1048576
    const float* src; unsigned short* dst; int k;
    if (id < per){ src = w1; dst = w1b; k = id; }
    else         { src = w2; dst = w2b; k = id - per; }
    const float4* s = (const float4*)(src + (size_t)k*8);
    float4 a = s[0], b = s[1];
    uint4 o;
    o.x = (unsigned)f2bf(a.x) | ((unsigned)f2bf(a.y)<<16);
    o.y = (unsigned)f2bf(a.z) | ((unsigned)f2bf(a.w)<<16);
    o.z = (unsigned)f2bf(b.x) | ((unsigned)f2bf(b.y)<<16);
    o.w = (unsigned)f2bf(b.z) | ((unsigned)f2bf(b.w)<<16);
    *(uint4*)(dst + (size_t)k*8) = o;
  } else {
    // ---- router: one wave per token, fp64 logits -> exact top-2 ----
    int t = (bx - 8192)*4 + (tid>>6);
    int l = tid & 63;
    const float* xr = x + (size_t)t*D_MODEL;
    float xv[8];
    #pragma unroll
    for (int j=0;j<8;j++) xv[j] = xr[j*64+l];
    double lg[NEXP];
    #pragma unroll
    for (int e=0;e<NEXP;e++){
      const float* we = rw + e*D_MODEL;
      double s = 0.0;
      #pragma unroll
      for (int j=0;j<8;j++) s += (double)xv[j] * (double)we[j*64+l];
      #pragma unroll
      for (int off=32; off; off>>=1) s += __shfl_xor(s, off);
      lg[e] = s;
    }
    if (l==0){
      double mx = lg[0];
      #pragma unroll
      for (int e=1;e<NEXP;e++) if (lg[e]>mx) mx = lg[e];
      double p[NEXP], sum = 0.0;
      #pragma unroll
      for (int e=0;e<NEXP;e++){ p[e] = exp(lg[e]-mx); sum += p[e]; }
      #pragma unroll
      for (int e=0;e<NEXP;e++) p[e] /= sum;
      int i0 = 0;
      for (int e=1;e<NEXP;e++) if (p[e] > p[i0]) i0 = e;      // ties -> lower idx
      int i1 = (i0==0) ? 1 : 0;
      for (int e=0;e<NEXP;e++){ if (e==i0) continue; if (p[e] > p[i1]) i1 = e; }
      double s2 = p[i0] + p[i1] + 1e-9;
      pair_e[2*t]   = i0;  pair_e[2*t+1] = i1;
      pair_w[2*t]   = (float)(p[i0]/s2);
      pair_w[2*t+1] = (float)(p[i1]/s2);
    }
  }
}

// ---------------- count: LDS histogram, 8 global atomics per block ----------------
__global__ void count_kernel(const int* __restrict__ pair_e, int* __restrict__ hdr){
  __shared__ int cnt[NEXP];
  int tid = threadIdx.x;
  if (tid < NEXP) cnt[tid] = 0;
  __syncthreads();
  int base = blockIdx.x*1024;
  #pragma unroll
  for (int i=0;i<4;i++) atomicAdd(&cnt[pair_e[base + i*256 + tid]], 1);
  __syncthreads();
  if (tid < NEXP) atomicAdd(&hdr[HD_COUNTS+tid], cnt[tid]);
}

// ---------------- plan: padded offsets + tile table + gtk defaults ----------------
__global__ void plan_kernel(int* __restrict__ hdr, int* __restrict__ gtk){
  if (threadIdx.x==0){
    int off=0, nt=0;
    for (int e=0;e<NEXP;e++){
      hdr[HD_OFF+e]=off;
      int c = hdr[HD_COUNTS+e];
      int tiles = (c+127)>>7;
      for (int i=0;i<tiles;i++){ hdr[HD_TILE_E+nt]=e; hdr[HD_TILE_R+nt]=off+(i<<7); nt++; }
      off += tiles<<7;
    }
    hdr[HD_OFF+NEXP]=off;
    hdr[HD_NTILES]=nt;
  }
  for (int i=threadIdx.x; i<PMAX; i+=blockDim.x) gtk[i]=-1;
}

// -------- assign + gather: LDS rank, range reservation, then copy x rows --------
__global__ void assign_gather_kernel(const int* __restrict__ pair_e, int* __restrict__ hdr,
                                     int* __restrict__ gtk, const float* __restrict__ x,
                                     unsigned short* __restrict__ xg){
  __shared__ int cnt[NEXP];
  __shared__ int base[NEXP];
  __shared__ int rowbuf[256];
  int tid = threadIdx.x;
  if (tid < NEXP) cnt[tid] = 0;
  __syncthreads();
  int id = blockIdx.x*256 + tid;
  int e = pair_e[id];
  int myrank = atomicAdd(&cnt[e], 1);           // LDS atomic
  __syncthreads();
  if (tid < NEXP) base[tid] = atomicAdd(&hdr[HD_CURSOR+tid], cnt[tid]);  // 8 global/block
  __syncthreads();
  int row = hdr[HD_OFF+e] + base[e] + myrank;
  gtk[row] = id;
  rowbuf[tid] = row;
  __syncthreads();
  // gather: 4 pairs at a time, 64 lanes per pair, 8 elems/lane
  int grp = tid>>6, sub = tid&63;
  int base0 = blockIdx.x*256;
  for (int p = grp; p < 256; p += 4){
    int r = rowbuf[p];
    int t = (base0 + p)>>1;
    const float4* s = (const float4*)(x + (size_t)t*D_MODEL + sub*8);
    float4 a = s[0], b = s[1];
    uint4 o;
    o.x = (unsigned)f2bf(a.x) | ((unsigned)f2bf(a.y)<<16);
    o.y = (unsigned)f2bf(a.z) | ((unsigned)f2bf(a.w)<<16);
    o.z = (unsigned)f2bf(b.x) | ((unsigned)f2bf(b.y)<<16);
    o.w = (unsigned)f2bf(b.z) | ((unsigned)f2bf(b.w)<<16);
    *(uint4*)(xg + (size_t)r*D_MODEL + sub*8) = o;
  }
}

// ---------------- GEMM1: 128x256 tile, 512 threads (8 waves 2Mx4N), BK=64 ----------
// A=xg [PMAX][512] bf16; B=w1b [NEXP][2048][512] bf16 (B^T). 2-phase counted-vmcnt.
// out h = relu(acc+bias) bf16. LDS 96KB -> 1 block/CU (16 waves).
__global__ __launch_bounds__(512,2) void gemm1_k(
    const unsigned short* __restrict__ A,
    const unsigned short* __restrict__ Bw,
    const float* __restrict__ bias,
    unsigned short* __restrict__ outH,
    const int* __restrict__ hdr)
{
  constexpr int NWG = MAXT*8;                  // 576
  __shared__ __align__(16) unsigned short As[2*128*64];   // 32KB
  __shared__ __align__(16) unsigned short Bs[2*256*64];   // 64KB

  int wg  = blockIdx.x;
  int swz = (wg & 7)*(NWG/8) + (wg >> 3);
  int m   = swz >> 3;
  int n0  = (swz & 7) << 8;

  if (m >= hdr[HD_NTILES]) return;
  int e    = hdr[HD_TILE_E+m];
  int row0 = hdr[HD_TILE_R+m];

  int tid = threadIdx.x;
  int w = tid>>6, l = tid&63;
  int wm = w>>2, wn = w&3;

  const unsigned short* Ag = A  + (size_t)row0*D_MODEL;
  const unsigned short* Bg = Bw + (size_t)e*DFF*D_MODEL + (size_t)n0*D_MODEL;

  f32x4 acc[4][4];
  f32x4 zz = {0.f,0.f,0.f,0.f};
  #pragma unroll
  for (int i=0;i<4;i++)
    #pragma unroll
    for (int j=0;j<4;j++) acc[i][j] = zz;

  int srow = (w<<3) + (l>>3);     // 0..63 per issue
  int c8   = l&7;
  char* AsB = (char*)As;
  char* BsB = (char*)Bs;

  auto stage = [&](int b, int kt){
    #pragma unroll
    for (int i=0;i<2;i++){
      int r  = i*64 + srow;
      int sc = (c8 ^ (r&7))*8;
      const unsigned short* ga = Ag + (size_t)r*D_MODEL + kt*64 + sc;
      int ldso = b*16384 + i*8192 + w*1024 + l*16;
      __builtin_amdgcn_global_load_lds((const __attribute__((address_space(1))) void*)ga,
                                       (__attribute__((address_space(3))) void*)(AsB + ldso), 16, 0, 0);
    }
    #pragma unroll
    for (int i=0;i<4;i++){
      int r  = i*64 + srow;
      int sc = (c8 ^ (r&7))*8;
      const unsigned short* gb = Bg + (size_t)r*D_MODEL + kt*64 + sc;
      int ldso = b*32768 + i*8192 + w*1024 + l*16;
      __builtin_amdgcn_global_load_lds((const __attribute__((address_space(1))) void*)gb,
                                       (__attribute__((address_space(3))) void*)(BsB + ldso), 16, 0, 0);
    }
  };

  auto compute = [&](int b){
    #pragma unroll
    for (int kk=0;kk<2;kk++){
      bf16x8 av[4], bv[4];
      #pragma unroll
      for (int mi=0;mi<4;mi++){
        int r  = (wm<<6) + (mi<<4) + (l&15);
        int ch = ((kk<<2) + (l>>4)) ^ (r&7);
        av[mi] = *(const bf16x8*)(AsB + b*16384 + r*128 + ch*16);
      }
      #pragma unroll
      for (int ni=0;ni<4;ni++){
        int r  = (wn<<6) + (ni<<4) + (l&15);
        int ch = ((kk<<2) + (l>>4)) ^ (r&7);
        bv[ni] = *(const bf16x8*)(BsB + b*32768 + r*128 + ch*16);
      }
      #pragma unroll
      for (int mi=0;mi<4;mi++)
        #pragma unroll
        for (int ni=0;ni<4;ni++)
          acc[mi][ni] = __builtin_amdgcn_mfma_f32_16x16x32_bf16(av[mi], bv[ni], acc[mi][ni], 0,0,0);
    }
  };

  stage(0, 0);
  int cur = 0;
  for (int kt=0; kt<D_MODEL/64-1; ++kt){
    stage(cur^1, kt+1);
    wait_vm<6>();
    RAW_BARRIER();
    compute(cur);
    asm volatile("s_waitcnt lgkmcnt(0)" ::: "memory");
    RAW_BARRIER();
    cur ^= 1;
  }
  wait_vm<0>();
  RAW_BARRIER();
  compute(cur);

  int lc = l&15, lq = l>>4;
  #pragma unroll
  for (int ni=0;ni<4;ni++){
    int col = n0 + (wn<<6) + (ni<<4) + lc;
    float bcol = bias[e*DFF + col];
    #pragma unroll
    for (int mi=0;mi<4;mi++){
      int rbase = row0 + (wm<<6) + (mi<<4) + lq*4;
      #pragma unroll
      for (int q=0;q<4;q++){
        float v = acc[mi][ni][q] + bcol;
        v = v>0.f ? v : 0.f;
        outH[(size_t)(rbase+q)*DFF + col] = f2bf(v);
      }
    }
  }
}

// ---------------- GEMM2: 64x128 tile, 256 threads (4 waves 1Mx4N), BK=64 ----------
// A=h [PMAX][2048] bf16; B=w2b [NEXP][512][2048] bf16 (B^T). 3 blocks/CU (48KB LDS).
// epilogue: atomicAdd(out[token], pair_w*(acc+bias)) — exactly 2 fp32 adds/elem.
__global__ __launch_bounds__(256,3) void gemm2_k(
    const unsigned short* __restrict__ A,
    const unsigned short* __restrict__ Bw,
    const float* __restrict__ bias,
    float* __restrict__ outO,
    const float* __restrict__ pair_w,
    const int* __restrict__ hdr,
    const int* __restrict__ gtk)
{
  constexpr int NWG = 2*MAXT*4;                // 576
  __shared__ __align__(16) unsigned short As[2*64*64];    // 16KB
  __shared__ __align__(16) unsigned short Bs[2*128*64];   // 32KB

  int wg  = blockIdx.x;
  int swz = (wg & 7)*(NWG/8) + (wg >> 3);
  int m   = swz >> 2;
  int n0  = (swz & 3) << 7;

  if (m >= 2*hdr[HD_NTILES]) return;
  int e    = hdr[HD_TILE_E+(m>>1)];
  int row0 = hdr[HD_TILE_R+(m>>1)] + ((m&1)<<6);

  int tid = threadIdx.x;
  int w = tid>>6, l = tid&63;

  const unsigned short* Ag = A  + (size_t)row0*DFF;
  const unsigned short* Bg = Bw + (size_t)e*D_MODEL*DFF + (size_t)n0*DFF;

  f32x4 acc[4][2];
  f32x4 zz = {0.f,0.f,0.f,0.f};
  #pragma unroll
  for (int i=0;i<4;i++)
    #pragma unroll
    for (int j=0;j<2;j++) acc[i][j] = zz;

  int srow = (w<<3) + (l>>3);     // 0..31 per issue
  int c8   = l&7;
  char* AsB = (char*)As;
  char* BsB = (char*)Bs;

  auto stage = [&](int b, int kt){
    #pragma unroll
    for (int i=0;i<2;i++){
      int r  = i*32 + srow;
      int sc = (c8 ^ (r&7))*8;
      const unsigned short* ga = Ag + (size_t)r*DFF + kt*64 + sc;
      int ldso = b*8192 + i*4096 + w*1024 + l*16;
      __builtin_amdgcn_global_load_lds((const __attribute__((address_space(1))) void*)ga,
                                       (__attribute__((address_space(3))) void*)(AsB + ldso), 16, 0, 0);
    }
    #pragma unroll
    for (int i=0;i<4;i++){
      int r  = i*32 + srow;
      int sc = (c8 ^ (r&7))*8;
      const unsigned short* gb = Bg + (size_t)r*DFF + kt*64 + sc;
      int ldso = b*16384 + i*4096 + w*1024 + l*16;
      __builtin_amdgcn_global_load_lds((const __attribute__((address_space(1))) void*)gb,
                                       (__attribute__((address_space(3))) void*)(BsB + ldso), 16, 0, 0);
    }
  };

  auto compute = [&](int b){
    #pragma unroll
    for (int kk=0;kk<2;kk++){
      bf16x8 av[4], bv[2];
      #pragma unroll
      for (int mi=0;mi<4;mi++){
        int r  = (mi<<4) + (l&15);
        int ch = ((kk<<2) + (l>>4)) ^ (r&7);
        av[mi] = *(const bf16x8*)(AsB + b*8192 + r*128 + ch*16);
      }
      #pragma unroll
      for (int ni=0;ni<2;ni++){
        int r  = (w<<5) + (ni<<4) + (l&15);
        int ch = ((kk<<2) + (l>>4)) ^ (r&7);
        bv[ni] = *(const bf16x8*)(BsB + b*16384 + r*128 + ch*16);
      }
      #pragma unroll
      for (int mi=0;mi<4;mi++)
        #pragma unroll
        for (int ni=0;ni<2;ni++)
          acc[mi][ni] = __builtin_amdgcn_mfma_f32_16x16x32_bf16(av[mi], bv[ni], acc[mi][ni], 0,0,0);
    }
  };

  stage(0, 0);
  int cur = 0;
  for (int kt=0; kt<DFF/64-1; ++kt){
    stage(cur^1, kt+1);
    wait_vm<6>();
    RAW_BARRIER();
    compute(cur);
    asm volatile("s_waitcnt lgkmcnt(0)" ::: "memory");
    RAW_BARRIER();
    cur ^= 1;
  }
  wait_vm<0>();
  RAW_BARRIER();
  compute(cur);

  int lc = l&15, lq = l>>4;
  #pragma unroll
  for (int ni=0;ni<2;ni++){
    int col = n0 + (w<<5) + (ni<<4) + lc;
    float bcol = bias[e*D_MODEL + col];
    #pragma unroll
    for (int mi=0;mi<4;mi++){
      int rbase = row0 + (mi<<4) + lq*4;
      #pragma unroll
      for (int q=0;q<4;q++){
        int gr = rbase + q;
        float v = acc[mi][ni][q] + bcol;
        int tk = gtk[gr];
        if (tk>=0){
          float wgt = pair_w[tk];
          atomicAdd(&outO[(size_t)(tk>>1)*D_MODEL + col], wgt*v);
        }
      }
    }
  }
}

extern "C" void kernel_launch(void* const* d_in, const int* in_sizes, int n_in,
                              void* d_out, int out_size, void* d_ws, size_t ws_size,
                              hipStream_t stream){
  const float* x  = (const float*)d_in[0];
  const float* rw = (const float*)d_in[1];
  const float* w1 = (const float*)d_in[2];
  const float* b1 = (const float*)d_in[3];
  const float* w2 = (const float*)d_in[4];
  const float* b2 = (const float*)d_in[5];
  float* out = (float*)d_out;

  // ws layout (bytes):
  const size_t OFF_HDR  = 0;
  const size_t OFF_PE   = 1024;
  const size_t OFF_PW   = 66560;
  const size_t OFF_GTK  = 99328;
  const size_t OFF_XG   = 180224;
  const size_t OFF_W1B  = OFF_XG  + (size_t)PMAX*D_MODEL*2;        // +9,437,184
  const size_t OFF_W2B  = OFF_W1B + (size_t)NEXP*DFF*D_MODEL*2;    // +16,777,216
  const size_t OFF_H    = OFF_W2B + (size_t)NEXP*DFF*D_MODEL*2;    // +16,777,216
  const size_t WS_NEED  = OFF_H   + (size_t)PMAX*DFF*2;            // +37,748,736 = ~80.9 MB
  if (ws_size < WS_NEED) return;   // refuse to scribble OOB (fails absmax cleanly)

  char* ws = (char*)d_ws;
  int*   hdr    = (int*)(ws + OFF_HDR);
  int*   pair_e = (int*)(ws + OFF_PE);
  float* pair_w = (float*)(ws + OFF_PW);
  int*   gtk    = (int*)(ws + OFF_GTK);
  unsigned short* xg  = (unsigned short*)(ws + OFF_XG);
  unsigned short* w1b = (unsigned short*)(ws + OFF_W1B);
  unsigned short* w2b = (unsigned short*)(ws + OFF_W2B);
  unsigned short* h   = (unsigned short*)(ws + OFF_H);

  hipMemsetAsync(hdr, 0, 1024, stream);
  hipMemsetAsync(out, 0, (size_t)LTOK*D_MODEL*sizeof(float), stream);
  prep_kernel<<<9216, 256, 0, stream>>>(w1, w2, w1b, w2b, x, rw, pair_e, pair_w);
  count_kernel<<<NPAIR/1024, 256, 0, stream>>>(pair_e, hdr);
  plan_kernel<<<1, 256, 0, stream>>>(hdr, gtk);
  assign_gather_kernel<<<NPAIR/256, 256, 0, stream>>>(pair_e, hdr, gtk, x, xg);
  gemm1_k<<<MAXT*8, 512, 0, stream>>>(xg, w1b, b1, h, hdr);
  gemm2_k<<<2*MAXT*4, 256, 0, stream>>>(h, w2b, b2, out, pair_w, hdr, gtk);
}